// Round 10
// baseline (402.426 us; speedup 1.0000x reference)
//
#include <hip/hip_runtime.h>
#include <stdint.h>

typedef unsigned short u16;
typedef __bf16 bf16x8 __attribute__((ext_vector_type(8)));
typedef unsigned short u16x8 __attribute__((ext_vector_type(8)));
typedef unsigned short u16x4 __attribute__((ext_vector_type(4)));
typedef float f32x4 __attribute__((ext_vector_type(4)));

#define BSZ 2
#define SEQ 2048
#define DIM 1024
#define D_INNER 2048
#define DT_RANK 64
#define D_STATE 16
#define XPROJ_N 96   // DT_RANK + 2*D_STATE
#define NCHUNK 32
#define CHUNK_T 64   // SEQ / NCHUNK
#define LOG2E 1.44269504f

#define N_X   4194304
#define N_W   4194304
#define N_WX  196608
#define N_WDT 131072
#define N_WO  2097152
#define N_XD  393216

__device__ __forceinline__ float bf2f(u16 h) {
    return __uint_as_float(((unsigned)h) << 16);
}
__device__ __forceinline__ u16 f2bf(float f) {
    unsigned u = __float_as_uint(f);
    unsigned r = (u + 0x7FFFu + ((u >> 16) & 1u)) >> 16;
    return (u16)r;
}

__device__ __forceinline__ f32x4 mfma16(bf16x8 a, bf16x8 b, f32x4 c) {
    return __builtin_amdgcn_mfma_f32_16x16x32_bf16(a, b, c, 0, 0, 0);
}

__device__ __forceinline__ void gload_lds16(const void* g, void* l) {
    __builtin_amdgcn_global_load_lds(
        (const __attribute__((address_space(1))) unsigned int*)(uintptr_t)g,
        (__attribute__((address_space(3))) unsigned int*)(uintptr_t)l,
        16, 0, 0);
}

// vectorized x4 split: f32x4 -> bf16 hi/lo x4
__device__ __forceinline__ void split4(const float* __restrict__ in,
                                       u16* __restrict__ hi, u16* __restrict__ lo,
                                       long i)
{
    f32x4 v = *(const f32x4*)(in + i);
    u16x4 h, l;
    #pragma unroll
    for (int j = 0; j < 4; j++) {
        u16 hh = f2bf(v[j]);
        h[j] = hh;
        l[j] = f2bf(v[j] - bf2f(hh));
    }
    *(u16x4*)(hi + i) = h;
    *(u16x4*)(lo + i) = l;
}

// split x, W_in, W_xproj, W_dt -> bf16 hi/lo, one launch, x4 vectorized
__global__ __launch_bounds__(256)
void megasplit4(const float* __restrict__ x,  u16* __restrict__ xh,  u16* __restrict__ xl,
                const float* __restrict__ w,  u16* __restrict__ wh,  u16* __restrict__ wl,
                const float* __restrict__ wx, u16* __restrict__ wxh, u16* __restrict__ wxl,
                const float* __restrict__ wd, u16* __restrict__ wdh, u16* __restrict__ wdl)
{
    long i = ((long)blockIdx.x * 256 + threadIdx.x) * 4;
    if (i < N_X) { split4(x, xh, xl, i); return; }
    i -= N_X;
    if (i < N_W) { split4(w, wh, wl, i); return; }
    i -= N_W;
    if (i < N_WX) { split4(wx, wxh, wxl, i); return; }
    i -= N_WX;
    if (i < N_WDT) { split4(wd, wdh, wdl, i); }
}

// phase sync brackets (m201 discipline, proven in R2)
#define PH_TOP                                                                \
    __builtin_amdgcn_sched_barrier(0);                                        \
    __builtin_amdgcn_s_barrier();                                             \
    asm volatile("s_waitcnt lgkmcnt(0)" ::: "memory");                        \
    __builtin_amdgcn_sched_barrier(0);                                        \
    __builtin_amdgcn_s_setprio(1);
#define PH_BOT                                                                \
    __builtin_amdgcn_s_setprio(0);                                            \
    __builtin_amdgcn_sched_barrier(0);                                        \
    __builtin_amdgcn_s_barrier();

// ========== GEMM1: 128x128 tile, TERM-FUSED, 3-phase, 2 blocks/CU ==========
// xz = x @ W_in^T, 3-term hi/lo (ah*bh + ah*bl + al*bh).
// R10: same 6-phase-proven bracket discipline per phase, but tile shrunk
// 256^2 -> 128^2 (256 thr, 4 waves of 64x64, acc[4][4]) so LDS drops to
// 64KB -> 2 blocks/CU. Rationale: measured 33% barrier-stall at 1 blk/CU
// (MfmaUtil 49, Occ 21); hand-scheduling failed twice (R3/R6); co-resident
// blocks let HW interleave across barriers (m114/m103: 128^2 + multi-block
// beats 256^2 on barrier-locked structures). L3 holds all inputs (67MB) so
// the extra panel re-reads stay off HBM.
// Per K-tile (BK=32), 3 phases:
//   P1: {read bh,ah ; stage AH,AL(kt+1)} | 16 MFMA ah x bh
//   P2: {read bl    ; stage BH,BL(kt+1)} | 16 MFMA ah x bl
//   P3: {read al}                        | 16 MFMA al x bh | vmcnt(0)
// fbh held live P1->P3 (R8-proven). LDS: 2 slots x 32KB {AH,AL,BH,BL}.
__global__ __launch_bounds__(256, 2)
void gemm256_xz(const u16* __restrict__ xh, const u16* __restrict__ xl,
                const u16* __restrict__ wh, const u16* __restrict__ wl,
                u16* __restrict__ xc, float* __restrict__ z)
{
    __shared__ u16 lds[32768];   // 2 slots x 16384 u16 (32KB)

    const int tid  = threadIdx.x;
    const int w    = tid >> 6;
    const int lane = tid & 63;
    const int r16  = lane & 15;
    const int quad = lane >> 4;
    const int wr   = w >> 1;     // 0..1 : rows wr*64..+63
    const int wc   = w & 1;      // 0..1 : cols wc*64..+63
    const long m0  = (long)blockIdx.y * 128;
    const long n0  = (long)blockIdx.x * 128;

    // staging cells: 512 cells (128 rows x 4 kc) of 16B; thread covers c0,c1
    const int c0 = tid, c1 = tid + 256;
    const int ma0 = c0 >> 2, kc0 = ((c0 & 3) ^ ((ma0 >> 1) & 3)) * 8;
    const int ma1 = c1 >> 2, kc1 = ((c1 & 3) ^ ((ma1 >> 1) & 3)) * 8;
    const int arow0 = ((int)m0 + ma0) * DIM + kc0;
    const int arow1 = ((int)m0 + ma1) * DIM + kc1;
    const int brow0 = ((int)n0 + ma0) * DIM + kc0;
    const int brow1 = ((int)n0 + ma1) * DIM + kc1;

    // fragment read offsets (u16 units)
    int caof[4], cbof[4];
    #pragma unroll
    for (int i = 0; i < 4; i++) {
        int m = wr * 64 + i * 16 + r16;
        caof[i] = (m * 4 + (quad ^ ((m >> 1) & 3))) * 8;
    }
    #pragma unroll
    for (int j = 0; j < 4; j++) {
        int n = wc * 64 + j * 16 + r16;
        cbof[j] = (n * 4 + (quad ^ ((n >> 1) & 3))) * 8;
    }

    f32x4 acc[4][4];
    #pragma unroll
    for (int i = 0; i < 4; i++)
        #pragma unroll
        for (int j = 0; j < 4; j++) acc[i][j] = {0.f, 0.f, 0.f, 0.f};

    // prologue: stage tile 0 fully into slot 0 (AH, AL, BH, BL)
    gload_lds16(xh + arow0, lds + c0 * 8);
    gload_lds16(xh + arow1, lds + c1 * 8);
    gload_lds16(xl + arow0, lds + 4096 + c0 * 8);
    gload_lds16(xl + arow1, lds + 4096 + c1 * 8);
    gload_lds16(wh + brow0, lds + 8192 + c0 * 8);
    gload_lds16(wh + brow1, lds + 8192 + c1 * 8);
    gload_lds16(wl + brow0, lds + 12288 + c0 * 8);
    gload_lds16(wl + brow1, lds + 12288 + c1 * 8);
    asm volatile("s_waitcnt vmcnt(0)" ::: "memory");
    __builtin_amdgcn_s_barrier();

    int kt = 0;
#define XZ_FTILE(CUR, SN)                                                     \
  {                                                                           \
    int st = kt + 1; if (st > 31) st = 31;                                    \
    const int kb = st * 32;                                                   \
    const u16* AHp = lds + (CUR) * 16384;                                     \
    const u16* ALp = AHp + 4096;                                              \
    const u16* BHp = AHp + 8192;                                              \
    const u16* BLp = AHp + 12288;                                             \
    u16* Sb = lds + (SN) * 16384;                                             \
    bf16x8 fa[4], fbh[4], fbl[4];                                             \
    /* P1: {bh, ah ; stage AH,AL(st)} | 16 MFMA ah x bh */                    \
    _Pragma("unroll") for (int j = 0; j < 4; j++)                             \
        fbh[j] = *(const bf16x8*)(BHp + cbof[j]);                             \
    _Pragma("unroll") for (int i = 0; i < 4; i++)                             \
        fa[i] = *(const bf16x8*)(AHp + caof[i]);                              \
    gload_lds16(xh + arow0 + kb, Sb + c0 * 8);                                \
    gload_lds16(xh + arow1 + kb, Sb + c1 * 8);                                \
    gload_lds16(xl + arow0 + kb, Sb + 4096 + c0 * 8);                         \
    gload_lds16(xl + arow1 + kb, Sb + 4096 + c1 * 8);                         \
    PH_TOP                                                                    \
    _Pragma("unroll") for (int i = 0; i < 4; i++)                             \
      _Pragma("unroll") for (int j = 0; j < 4; j++)                           \
        acc[i][j] = mfma16(fa[i], fbh[j], acc[i][j]);                         \
    PH_BOT                                                                    \
    /* P2: {bl ; stage BH,BL(st)} | 16 MFMA ah x bl */                        \
    _Pragma("unroll") for (int j = 0; j < 4; j++)                             \
        fbl[j] = *(const bf16x8*)(BLp + cbof[j]);                             \
    gload_lds16(wh + brow0 + kb, Sb + 8192 + c0 * 8);                         \
    gload_lds16(wh + brow1 + kb, Sb + 8192 + c1 * 8);                         \
    gload_lds16(wl + brow0 + kb, Sb + 12288 + c0 * 8);                        \
    gload_lds16(wl + brow1 + kb, Sb + 12288 + c1 * 8);                        \
    PH_TOP                                                                    \
    _Pragma("unroll") for (int i = 0; i < 4; i++)                             \
      _Pragma("unroll") for (int j = 0; j < 4; j++)                           \
        acc[i][j] = mfma16(fa[i], fbl[j], acc[i][j]);                         \
    PH_BOT                                                                    \
    /* P3: {al} | 16 MFMA al x bh (fbh live) | vmcnt(0) tile boundary */      \
    _Pragma("unroll") for (int i = 0; i < 4; i++)                             \
        fa[i] = *(const bf16x8*)(ALp + caof[i]);                              \
    PH_TOP                                                                    \
    _Pragma("unroll") for (int i = 0; i < 4; i++)                             \
      _Pragma("unroll") for (int j = 0; j < 4; j++)                           \
        acc[i][j] = mfma16(fa[i], fbh[j], acc[i][j]);                         \
    __builtin_amdgcn_s_setprio(0);                                            \
    __builtin_amdgcn_sched_barrier(0);                                        \
    asm volatile("s_waitcnt vmcnt(0)" ::: "memory");                          \
    __builtin_amdgcn_s_barrier();                                             \
    kt++;                                                                     \
  }

    #pragma unroll 1
    for (int it = 0; it < 16; it++) {
        XZ_FTILE(0, 1)
        XZ_FTILE(1, 0)
    }
#undef XZ_FTILE

    asm volatile("s_waitcnt vmcnt(0)" ::: "memory");  // drain before endpgm

    // epilogue: cols [0,2048) -> xc bf16, [2048,4096) -> z f32 (block-uniform)
    const bool isz = (n0 >= 2048);
    #pragma unroll
    for (int i = 0; i < 4; i++) {
        #pragma unroll
        for (int j = 0; j < 4; j++) {
            long col = n0 + wc * 64 + j * 16 + r16;
            #pragma unroll
            for (int r = 0; r < 4; r++) {
                long row = m0 + wr * 64 + i * 16 + quad * 4 + r;
                if (!isz) xc[row * (long)D_INNER + col] = f2bf(acc[i][j][r]);
                else      z[row * (long)D_INNER + (col - D_INNER)] = acc[i][j][r];
            }
        }
    }
}

// ===================== GEMM4: term-fused, split-K=2 (R9-proven) =============
// opre[kz] = yb[:,half_kz] @ (Wh + Wl)[:,half_kz]^T — both hi/lo terms per
// block into ONE accumulator, A staged once per K-tile.
// Geometry: BM=128, BN=256, 8 waves (2M x 4N, 64x64/wave, acc[4][4]),
// grid (4,32,2) = 256 blocks. LDS: 2 slots x {A 8KB | Bh 16KB | Bl 16KB}.
__global__ __launch_bounds__(512, 2)
void gemm256_out(const u16* __restrict__ A, const u16* __restrict__ Bh,
                 const u16* __restrict__ Bl, float* __restrict__ OutBase)
{
    __shared__ u16 lds[40960];   // 2 slots x 20480 u16

    const int tid  = threadIdx.x;
    const int w    = tid >> 6;
    const int lane = tid & 63;
    const int r16  = lane & 15;
    const int quad = lane >> 4;
    const int wr   = w >> 2;           // 0..1 : rows wr*64
    const int wc   = w & 3;            // 0..3 : cols wc*64
    const long m0  = (long)blockIdx.y * 128;
    const long n0  = (long)blockIdx.x * 256;
    const int  kz  = blockIdx.z;
    const int  kbase = kz * 1024;
    float* Out = OutBase + (long)kz * 4194304;

    // A staging: 512 cells (128 rows x 4 kc), thread stages 1 cell
    const int maA = tid >> 2, kcA = ((tid & 3) ^ ((maA >> 1) & 3)) * 8;
    const int arow = ((int)m0 + maA) * D_INNER + kbase + kcA;
    // B staging: 1024 cells (256 rows x 4 kc), thread stages c0, c1
    const int c0 = tid, c1 = tid + 512;
    const int mb0 = c0 >> 2, kb0 = ((c0 & 3) ^ ((mb0 >> 1) & 3)) * 8;
    const int mb1 = c1 >> 2, kb1 = ((c1 & 3) ^ ((mb1 >> 1) & 3)) * 8;
    const int brow0 = ((int)n0 + mb0) * D_INNER + kbase + kb0;
    const int brow1 = ((int)n0 + mb1) * D_INNER + kbase + kb1;

    int caof[4], cbof[4];
    #pragma unroll
    for (int i = 0; i < 4; i++) {
        int m = wr * 64 + i * 16 + r16;
        caof[i] = (m * 4 + (quad ^ ((m >> 1) & 3))) * 8;
    }
    #pragma unroll
    for (int j = 0; j < 4; j++) {
        int n = wc * 64 + j * 16 + r16;
        cbof[j] = (n * 4 + (quad ^ ((n >> 1) & 3))) * 8;
    }

    f32x4 acc[4][4];
    #pragma unroll
    for (int i = 0; i < 4; i++)
        #pragma unroll
        for (int j = 0; j < 4; j++) acc[i][j] = {0.f, 0.f, 0.f, 0.f};

    // prologue: stage tile 0 -> slot 0
    gload_lds16(A  + arow,  lds + tid * 8);
    gload_lds16(Bh + brow0, lds + 4096 + c0 * 8);
    gload_lds16(Bh + brow1, lds + 4096 + c1 * 8);
    gload_lds16(Bl + brow0, lds + 12288 + c0 * 8);
    gload_lds16(Bl + brow1, lds + 12288 + c1 * 8);
    asm volatile("s_waitcnt vmcnt(0)" ::: "memory");
    __builtin_amdgcn_s_barrier();

    int kt = 0;
#define O2_TILE(CUR, SN)                                                      \
  {                                                                           \
    int st = kt + 1; if (st > 31) st = 31;                                    \
    const int kb = st * 32;                                                   \
    const u16* Ap  = lds + (CUR) * 20480;                                     \
    const u16* BHp = Ap + 4096;                                               \
    const u16* BLp = Ap + 12288;                                              \
    u16* Sb = lds + (SN) * 20480;                                             \
    bf16x8 fa[4], fb[4];                                                      \
    /* P1: {bh4, a4 ; stage A(st)} | 16 MFMA a x bh */                        \
    _Pragma("unroll") for (int j = 0; j < 4; j++)                             \
        fb[j] = *(const bf16x8*)(BHp + cbof[j]);                              \
    _Pragma("unroll") for (int i = 0; i < 4; i++)                             \
        fa[i] = *(const bf16x8*)(Ap + caof[i]);                               \
    gload_lds16(A + arow + kb, Sb + tid * 8);                                 \
    PH_TOP                                                                    \
    _Pragma("unroll") for (int i = 0; i < 4; i++)                             \
      _Pragma("unroll") for (int j = 0; j < 4; j++)                           \
        acc[i][j] = mfma16(fa[i], fb[j], acc[i][j]);                          \
    PH_BOT                                                                    \
    /* P2: {bl4 ; stage Bh,Bl(st)} | 16 MFMA a x bl | vmcnt(0) */             \
    _Pragma("unroll") for (int j = 0; j < 4; j++)                             \
        fb[j] = *(const bf16x8*)(BLp + cbof[j]);                              \
    gload_lds16(Bh + brow0 + kb, Sb + 4096 + c0 * 8);                         \
    gload_lds16(Bh + brow1 + kb, Sb + 4096 + c1 * 8);                         \
    gload_lds16(Bl + brow0 + kb, Sb + 12288 + c0 * 8);                        \
    gload_lds16(Bl + brow1 + kb, Sb + 12288 + c1 * 8);                        \
    PH_TOP                                                                    \
    _Pragma("unroll") for (int i = 0; i < 4; i++)                             \
      _Pragma("unroll") for (int j = 0; j < 4; j++)                           \
        acc[i][j] = mfma16(fa[i], fb[j], acc[i][j]);                          \
    __builtin_amdgcn_s_setprio(0);                                            \
    __builtin_amdgcn_sched_barrier(0);                                        \
    asm volatile("s_waitcnt vmcnt(0)" ::: "memory");                          \
    __builtin_amdgcn_s_barrier();                                             \
    kt++;                                                                     \
  }

    #pragma unroll 1
    for (int it = 0; it < 16; it++) {
        O2_TILE(0, 1)
        O2_TILE(1, 0)
    }
#undef O2_TILE

    asm volatile("s_waitcnt vmcnt(0)" ::: "memory");

    #pragma unroll
    for (int i = 0; i < 4; i++) {
        #pragma unroll
        for (int j = 0; j < 4; j++) {
            long col = n0 + wc * 64 + j * 16 + r16;
            #pragma unroll
            for (int r = 0; r < 4; r++) {
                long row = m0 + wr * 64 + i * 16 + quad * 4 + r;
                Out[row * (long)DIM + col] = acc[i][j][r];
            }
        }
    }
}

// GEMM2 (K=64): 32x32 per wave, 3-term, softplus epilogue
__global__ __launch_bounds__(64)
void gemm_dt32(const u16* __restrict__ Ah, const u16* __restrict__ Al, int lda,
               const u16* __restrict__ Bh, const u16* __restrict__ Bl, int ldb,
               float* __restrict__ C, int ldc, const float* __restrict__ bias)
{
    const int lane = threadIdx.x;
    const int r16  = lane & 15;
    const int quad = lane >> 4;
    const long m0 = (long)blockIdx.y * 32;
    const long n0 = (long)blockIdx.x * 32;

    const u16* Ah0 = Ah + (m0 + r16) * (long)lda + quad * 8;
    const u16* Ah1 = Ah0 + 16L * lda;
    const u16* Al0 = Al + (m0 + r16) * (long)lda + quad * 8;
    const u16* Al1 = Al0 + 16L * lda;
    const u16* Bh0 = Bh + (n0 + r16) * (long)ldb + quad * 8;
    const u16* Bh1 = Bh0 + 16L * ldb;
    const u16* Bl0 = Bl + (n0 + r16) * (long)ldb + quad * 8;
    const u16* Bl1 = Bl0 + 16L * ldb;

    f32x4 acc00 = {0,0,0,0}, acc01 = {0,0,0,0}, acc10 = {0,0,0,0}, acc11 = {0,0,0,0};

    #pragma unroll
    for (int k = 0; k < DT_RANK; k += 32) {
        bf16x8 a0h = *(const bf16x8*)(Ah0 + k);
        bf16x8 a1h = *(const bf16x8*)(Ah1 + k);
        bf16x8 a0l = *(const bf16x8*)(Al0 + k);
        bf16x8 a1l = *(const bf16x8*)(Al1 + k);
        bf16x8 b0h = *(const bf16x8*)(Bh0 + k);
        bf16x8 b1h = *(const bf16x8*)(Bh1 + k);
        bf16x8 b0l = *(const bf16x8*)(Bl0 + k);
        bf16x8 b1l = *(const bf16x8*)(Bl1 + k);
        acc00 = mfma16(a0h, b0h, acc00); acc00 = mfma16(a0h, b0l, acc00); acc00 = mfma16(a0l, b0h, acc00);
        acc01 = mfma16(a0h, b1h, acc01); acc01 = mfma16(a0h, b1l, acc01); acc01 = mfma16(a0l, b1h, acc01);
        acc10 = mfma16(a1h, b0h, acc10); acc10 = mfma16(a1h, b0l, acc10); acc10 = mfma16(a1l, b0h, acc10);
        acc11 = mfma16(a1h, b1h, acc11); acc11 = mfma16(a1h, b1l, acc11); acc11 = mfma16(a1l, b1h, acc11);
    }

    #pragma unroll
    for (int i = 0; i < 2; i++) {
        #pragma unroll
        for (int j = 0; j < 2; j++) {
            f32x4 v = (i == 0) ? (j == 0 ? acc00 : acc01) : (j == 0 ? acc10 : acc11);
            long col = n0 + j * 16 + r16;
            #pragma unroll
            for (int r = 0; r < 4; r++) {
                long row = m0 + i * 16 + quad * 4 + r;
                float x = v[r] + bias[col];
                x = (x > 15.f) ? x : log1pf(__expf(x));
                C[row * (long)ldc + col] = x;
            }
        }
    }
}

// GEMM3: partial[kz] = u @ W_xproj^T over K-slice kz (no atomics)
__global__ __launch_bounds__(64)
void gemm3_skp(const u16* __restrict__ A, int lda,
               const u16* __restrict__ Bh, const u16* __restrict__ Bl, int ldb,
               float* __restrict__ Cpart, int ldc, int K0)
{
    const int lane = threadIdx.x;
    const int r16  = lane & 15;
    const int quad = lane >> 4;
    const long m0 = (long)blockIdx.y * 32;
    const long n0 = (long)blockIdx.x * 32;
    const int kbase = blockIdx.z * K0;
    float* C = Cpart + (long)blockIdx.z * N_XD;

    const u16* Ap0 = A  + (m0 + r16) * (long)lda + quad * 8 + kbase;
    const u16* Ap1 = Ap0 + 16L * lda;
    const u16* Bh0 = Bh + (n0 + r16) * (long)ldb + quad * 8 + kbase;
    const u16* Bh1 = Bh0 + 16L * ldb;
    const u16* Bl0 = Bl + (n0 + r16) * (long)ldb + quad * 8 + kbase;
    const u16* Bl1 = Bl0 + 16L * ldb;

    f32x4 acc00 = {0,0,0,0}, acc01 = {0,0,0,0}, acc10 = {0,0,0,0}, acc11 = {0,0,0,0};

    for (int k = 0; k < K0; k += 32) {
        bf16x8 a0 = *(const bf16x8*)(Ap0 + k);
        bf16x8 a1 = *(const bf16x8*)(Ap1 + k);
        bf16x8 b0h = *(const bf16x8*)(Bh0 + k);
        bf16x8 b1h = *(const bf16x8*)(Bh1 + k);
        bf16x8 b0l = *(const bf16x8*)(Bl0 + k);
        bf16x8 b1l = *(const bf16x8*)(Bl1 + k);
        acc00 = mfma16(a0, b0h, acc00); acc00 = mfma16(a0, b0l, acc00);
        acc01 = mfma16(a0, b1h, acc01); acc01 = mfma16(a0, b1l, acc01);
        acc10 = mfma16(a1, b0h, acc10); acc10 = mfma16(a1, b0l, acc10);
        acc11 = mfma16(a1, b1h, acc11); acc11 = mfma16(a1, b1l, acc11);
    }

    #pragma unroll
    for (int i = 0; i < 2; i++) {
        #pragma unroll
        for (int j = 0; j < 2; j++) {
            f32x4 v = (i == 0) ? (j == 0 ? acc00 : acc01) : (j == 0 ? acc10 : acc11);
            long col = n0 + j * 16 + r16;
            #pragma unroll
            for (int r = 0; r < 4; r++) {
                long row = m0 + i * 16 + quad * 4 + r;
                C[row * (long)ldc + col] = v[r];
            }
        }
    }
}

// combine 8 gemm3 partials -> xdbc f32 + hi/lo split, x4 vectorized
__global__ __launch_bounds__(256)
void combine3(const float* __restrict__ part, float* __restrict__ xdbc,
              u16* __restrict__ hi, u16* __restrict__ lo)
{
    long i = ((long)blockIdx.x * 256 + threadIdx.x) * 4;
    if (i >= N_XD) return;
    f32x4 s = *(const f32x4*)(part + i);
    #pragma unroll
    for (int j = 1; j < 8; j++) {
        f32x4 p = *(const f32x4*)(part + (long)j * N_XD + i);
        s[0] += p[0]; s[1] += p[1]; s[2] += p[2]; s[3] += p[3];
    }
    *(f32x4*)(xdbc + i) = s;
    u16x4 h, l;
    #pragma unroll
    for (int j = 0; j < 4; j++) {
        u16 hh = f2bf(s[j]);
        h[j] = hh;
        l[j] = f2bf(s[j] - bf2f(hh));
    }
    *(u16x4*)(hi + i) = h;
    *(u16x4*)(lo + i) = l;
}

// depthwise causal conv(4) + bias + silu, 8 channels per thread
__global__ __launch_bounds__(256)
void conv_silu(const u16* __restrict__ xc, const float* __restrict__ cw,
               const float* __restrict__ cb, u16* __restrict__ u)
{
    long idx = ((long)blockIdx.x * 256 + threadIdx.x) * 8;
    int t  = (int)((idx >> 11) & 2047);
    int d0 = (int)(idx & 2047);

    bf16x8 xrow[4];
    #pragma unroll
    for (int j = 0; j < 4; j++) {
        int tt = t - 3 + j;
        if (tt >= 0) xrow[j] = *(const bf16x8*)(xc + idx + (long)(j - 3) * D_INNER);
        else         xrow[j] = bf16x8{0,0,0,0,0,0,0,0};
    }
    u16x8 out;
    #pragma unroll
    for (int e = 0; e < 8; e++) {
        int d = d0 + e;
        float acc = cb[d];
        #pragma unroll
        for (int j = 0; j < 4; j++)
            acc += cw[d * 4 + j] * (float)xrow[j][e];
        out[e] = f2bf(acc / (1.f + __expf(-acc)));
    }
    *(u16x8*)(u + idx) = out;
}

// ---- chunked parallel scan: pass A  (+ fused W_out hi/lo split) ------------
// R7-proven q-power fast path (guarded): Af[s] = (s+1)*Af[0] =>
// exp2(dl*Af[s]) = q^(s+1), ONE exp2 per t.
__global__ __launch_bounds__(256)
void scan_partA(const float* __restrict__ delta, const u16* __restrict__ u,
                const float* __restrict__ xdbc, const float* __restrict__ A_log,
                float* __restrict__ hbuf, float* __restrict__ sdelta,
                const float* __restrict__ wout, u16* __restrict__ wouth,
                u16* __restrict__ woutl)
{
    const int d = blockIdx.x * 256 + threadIdx.x;
    const int c = blockIdx.y;
    const int b = blockIdx.z;
    const int t0 = c * CHUNK_T;

    float Af[16];
    #pragma unroll
    for (int s = 0; s < 16; s++) Af[s] = -__expf(A_log[d * 16 + s]) * LOG2E;
    bool fast = true;
    #pragma unroll
    for (int s = 0; s < 16; s++)
        fast = fast && (fabsf(Af[s] - (float)(s + 1) * Af[0]) < 1e-3f * (float)(s + 1));

    float h[16];
    #pragma unroll
    for (int s = 0; s < 16; s++) h[s] = 0.f;
    float sd = 0.f;

    const float* dptr = delta + ((long)b * SEQ + t0) * D_INNER + d;
    const u16*   uptr = u     + ((long)b * SEQ + t0) * D_INNER + d;
    const float* xp   = xdbc  + ((long)b * SEQ + t0) * XPROJ_N;

    if (fast) {
        const float Af0 = Af[0];
        for (int t = 0; t < CHUNK_T; t++) {
            float dl = dptr[(long)t * D_INNER];
            float uu = bf2f(uptr[(long)t * D_INNER]);
            f32x4 B0 = *(const f32x4*)(xp + t * XPROJ_N + DT_RANK);
            f32x4 B1 = *(const f32x4*)(xp + t * XPROJ_N + DT_RANK + 4);
            f32x4 B2 = *(const f32x4*)(xp + t * XPROJ_N + DT_RANK + 8);
            f32x4 B3 = *(const f32x4*)(xp + t * XPROJ_N + DT_RANK + 12);
            float Bv[16] = {B0[0],B0[1],B0[2],B0[3], B1[0],B1[1],B1[2],B1[3],
                            B2[0],B2[1],B2[2],B2[3], B3[0],B3[1],B3[2],B3[3]};
            sd += dl;
            float dlu = dl * uu;
            float q = exp2f(dl * Af0);
            float dAc = 1.f;
            #pragma unroll
            for (int s = 0; s < 16; s++) {
                dAc *= q;
                h[s] = h[s] * dAc + dlu * Bv[s];
            }
        }
    } else {
        for (int t = 0; t < CHUNK_T; t++) {
            float dl = dptr[(long)t * D_INNER];
            float uu = bf2f(uptr[(long)t * D_INNER]);
            f32x4 B0 = *(const f32x4*)(xp + t * XPROJ_N + DT_RANK);
            f32x4 B1 = *(const f32x4*)(xp + t * XPROJ_N + DT_RANK + 4);
            f32x4 B2 = *(const f32x4*)(xp + t * XPROJ_N + DT_RANK + 8);
            f32x4 B3 = *(const f32x4*)(xp + t * XPROJ_N + DT_RANK + 12);
            float Bv[16] = {B0[0],B0[1],B0[2],B0[3], B1[0],B1[1],B1[2],B1[3],
                            B2[0],B2[1],B2[2],B2[3], B3[0],B3[1],B3[2],B3[3]};
            sd += dl;
            float dlu = dl * uu;
            #pragma unroll
            for (int s = 0; s < 16; s++)
                h[s] = h[s] * exp2f(dl * Af[s]) + dlu * Bv[s];
        }
    }

    float* hout = hbuf + ((long)(b * NCHUNK + c) * D_INNER + d) * 16;
    #pragma unroll
    for (int s = 0; s < 16; s++) hout[s] = h[s];
    sdelta[(long)(b * NCHUNK + c) * D_INNER + d] = sd;

    // fused W_out split: 131072 threads x 16 elems = 2097152 (exact)
    long tidg = (((long)b * NCHUNK + c) * 8 + blockIdx.x) * 256 + threadIdx.x;
    long base = tidg * 16;
    #pragma unroll
    for (int k = 0; k < 4; k++) split4(wout, wouth, woutl, base + 4 * k);
}

// ---- pass B: compose chunk boundaries (in-place: hbuf h_end -> h_in) -------
// R10: software-pipelined — prefetch next chunk's e/sd before the current
// store+compute (4 waves/CU only; serial L2 round-trips were exposed).
__global__ __launch_bounds__(256)
void scan_fixup(float* __restrict__ hbuf, const float* __restrict__ sdelta,
                const float* __restrict__ A_log)
{
    const int idx = blockIdx.x * 256 + threadIdx.x;
    const int ds = idx & (D_INNER * 16 - 1);
    const int b  = idx >> 15;
    const float Af = -__expf(A_log[ds]) * LOG2E;
    float hin = 0.f;
    long gi = (long)b * NCHUNK * (D_INNER * 16) + ds;
    long si = (long)b * NCHUNK * D_INNER + (ds >> 4);
    float e  = hbuf[gi];
    float sd = sdelta[si];
    #pragma unroll 4
    for (int c = 0; c < NCHUNK; c++) {
        int cn = (c + 1 < NCHUNK) ? (c + 1) : (NCHUNK - 1);
        long gin = (long)(b * NCHUNK + cn) * (D_INNER * 16) + ds;
        long sin = (long)(b * NCHUNK + cn) * D_INNER + (ds >> 4);
        float e2  = hbuf[gin];
        float sd2 = sdelta[sin];
        hbuf[gi] = hin;
        hin = e + exp2f(Af * sd) * hin;
        e = e2; sd = sd2; gi = gin;
    }
}

// ---- pass C: full scan from h_in, fused +u*D and *silu(z), write y (bf16) --
// Same q-power fast path as partA (guarded).
__global__ __launch_bounds__(256)
void scan_partC(const float* __restrict__ delta, const u16* __restrict__ u,
                const float* __restrict__ xdbc, const float* __restrict__ z,
                const float* __restrict__ A_log, const float* __restrict__ Dp,
                const float* __restrict__ hbuf, u16* __restrict__ y)
{
    const int d = blockIdx.x * 256 + threadIdx.x;
    const int c = blockIdx.y;
    const int b = blockIdx.z;
    const int t0 = c * CHUNK_T;

    float Af[16];
    #pragma unroll
    for (int s = 0; s < 16; s++) Af[s] = -__expf(A_log[d * 16 + s]) * LOG2E;
    bool fast = true;
    #pragma unroll
    for (int s = 0; s < 16; s++)
        fast = fast && (fabsf(Af[s] - (float)(s + 1) * Af[0]) < 1e-3f * (float)(s + 1));
    const float Dd = Dp[d];

    float h[16];
    const float* hin = hbuf + ((long)(b * NCHUNK + c) * D_INNER + d) * 16;
    #pragma unroll
    for (int s = 0; s < 16; s++) h[s] = hin[s];

    const float* dptr = delta + ((long)b * SEQ + t0) * D_INNER + d;
    const u16*   uptr = u     + ((long)b * SEQ + t0) * D_INNER + d;
    const float* zptr = z     + ((long)b * SEQ + t0) * D_INNER + d;
    const float* xp   = xdbc  + ((long)b * SEQ + t0) * XPROJ_N;
    u16* yptr = y + ((long)b * SEQ + t0) * D_INNER + d;

    if (fast) {
        const float Af0 = Af[0];
        for (int t = 0; t < CHUNK_T; t++) {
            float dl = dptr[(long)t * D_INNER];
            float uu = bf2f(uptr[(long)t * D_INNER]);
            float zl = zptr[(long)t * D_INNER];
            f32x4 B0 = *(const f32x4*)(xp + t * XPROJ_N + DT_RANK);
            f32x4 B1 = *(const f32x4*)(xp + t * XPROJ_N + DT_RANK + 4);
            f32x4 B2 = *(const f32x4*)(xp + t * XPROJ_N + DT_RANK + 8);
            f32x4 B3 = *(const f32x4*)(xp + t * XPROJ_N + DT_RANK + 12);
            f32x4 C0 = *(const f32x4*)(xp + t * XPROJ_N + DT_RANK + 16);
            f32x4 C1 = *(const f32x4*)(xp + t * XPROJ_N + DT_RANK + 20);
            f32x4 C2 = *(const f32x4*)(xp + t * XPROJ_N + DT_RANK + 24);
            f32x4 C3 = *(const f32x4*)(xp + t * XPROJ_N + DT_RANK + 28);
            float Bv[16] = {B0[0],B0[1],B0[2],B0[3], B1[0],B1[1],B1[2],B1[3],
                            B2[0],B2[1],B2[2],B2[3], B3[0],B3[1],B3[2],B3[3]};
            float Cv[16] = {C0[0],C0[1],C0[2],C0[3], C1[0],C1[1],C1[2],C1[3],
                            C2[0],C2[1],C2[2],C2[3], C3[0],C3[1],C3[2],C3[3]};
            float dlu = dl * uu;
            float q = exp2f(dl * Af0);
            float dAc = 1.f;
            float p0 = 0.f, p1 = 0.f, p2 = 0.f, p3 = 0.f;
            #pragma unroll
            for (int s = 0; s < 16; s += 4) {
                float dA0 = dAc * q;
                float dA1 = dA0 * q;
                float dA2 = dA1 * q;
                float dA3 = dA2 * q;
                dAc = dA3;
                h[s]   = h[s]   * dA0 + dlu * Bv[s];
                h[s+1] = h[s+1] * dA1 + dlu * Bv[s+1];
                h[s+2] = h[s+2] * dA2 + dlu * Bv[s+2];
                h[s+3] = h[s+3] * dA3 + dlu * Bv[s+3];
                p0 += h[s]   * Cv[s];
                p1 += h[s+1] * Cv[s+1];
                p2 += h[s+2] * Cv[s+2];
                p3 += h[s+3] * Cv[s+3];
            }
            float acc = (p0 + p1) + (p2 + p3);
            float sz = zl / (1.f + __expf(-zl));
            float yy = (acc + uu * Dd) * sz;
            yptr[(long)t * D_INNER] = f2bf(yy);
        }
    } else {
        for (int t = 0; t < CHUNK_T; t++) {
            float dl = dptr[(long)t * D_INNER];
            float uu = bf2f(uptr[(long)t * D_INNER]);
            float zl = zptr[(long)t * D_INNER];
            f32x4 B0 = *(const f32x4*)(xp + t * XPROJ_N + DT_RANK);
            f32x4 B1 = *(const f32x4*)(xp + t * XPROJ_N + DT_RANK + 4);
            f32x4 B2 = *(const f32x4*)(xp + t * XPROJ_N + DT_RANK + 8);
            f32x4 B3 = *(const f32x4*)(xp + t * XPROJ_N + DT_RANK + 12);
            f32x4 C0 = *(const f32x4*)(xp + t * XPROJ_N + DT_RANK + 16);
            f32x4 C1 = *(const f32x4*)(xp + t * XPROJ_N + DT_RANK + 20);
            f32x4 C2 = *(const f32x4*)(xp + t * XPROJ_N + DT_RANK + 24);
            f32x4 C3 = *(const f32x4*)(xp + t * XPROJ_N + DT_RANK + 28);
            float Bv[16] = {B0[0],B0[1],B0[2],B0[3], B1[0],B1[1],B1[2],B1[3],
                            B2[0],B2[1],B2[2],B2[3], B3[0],B3[1],B3[2],B3[3]};
            float Cv[16] = {C0[0],C0[1],C0[2],C0[3], C1[0],C1[1],C1[2],C1[3],
                            C2[0],C2[1],C2[2],C2[3], C3[0],C3[1],C3[2],C3[3]};
            float dlu = dl * uu;
            float p0 = 0.f, p1 = 0.f, p2 = 0.f, p3 = 0.f;
            #pragma unroll
            for (int s = 0; s < 16; s += 4) {
                h[s]   = h[s]   * exp2f(dl * Af[s])   + dlu * Bv[s];
                h[s+1] = h[s+1] * exp2f(dl * Af[s+1]) + dlu * Bv[s+1];
                h[s+2] = h[s+2] * exp2f(dl * Af[s+2]) + dlu * Bv[s+2];
                h[s+3] = h[s+3] * exp2f(dl * Af[s+3]) + dlu * Bv[s+3];
                p0 += h[s]   * Cv[s];
                p1 += h[s+1] * Cv[s+1];
                p2 += h[s+2] * Cv[s+2];
                p3 += h[s+3] * Cv[s+3];
            }
            float acc = (p0 + p1) + (p2 + p3);
            float sz = zl / (1.f + __expf(-zl));
            float yy = (acc + uu * Dd) * sz;
            yptr[(long)t * D_INNER] = f2bf(yy);
        }
    }
}

// layernorm over sum of 2 split-K partials (stride 4194304 floats apart)
__global__ __launch_bounds__(256)
void layernorm_kernel(const float* __restrict__ p0,
                      const float* __restrict__ gamma, const float* __restrict__ beta,
                      float* __restrict__ out)
{
    const long row = blockIdx.x;
    const long base = row * DIM;
    int tid = threadIdx.x;
    float v[4];
    float sum = 0.f, sq = 0.f;
    #pragma unroll
    for (int i = 0; i < 4; i++) {
        long c = base + tid + i * 256;
        v[i] = p0[c] + p0[c + 4194304];
        sum += v[i];
        sq  += v[i] * v[i];
    }
    #pragma unroll
    for (int off = 1; off < 64; off <<= 1) {
        sum += __shfl_xor(sum, off);
        sq  += __shfl_xor(sq, off);
    }
    __shared__ float ssum[4], ssq[4];
    int w = tid >> 6;
    if ((tid & 63) == 0) { ssum[w] = sum; ssq[w] = sq; }
    __syncthreads();
    float ts = ssum[0] + ssum[1] + ssum[2] + ssum[3];
    float tq = ssq[0] + ssq[1] + ssq[2] + ssq[3];
    float mean = ts * (1.f / DIM);
    float var  = tq * (1.f / DIM) - mean * mean;
    float rstd = rsqrtf(var + 1e-5f);
    float* o = out + base;
    #pragma unroll
    for (int i = 0; i < 4; i++) {
        int c = tid + i * 256;
        o[c] = (v[i] - mean) * rstd * gamma[c] + beta[c];
    }
}

extern "C" void kernel_launch(void* const* d_in, const int* in_sizes, int n_in,
                              void* d_out, int out_size, void* d_ws, size_t ws_size,
                              hipStream_t stream)
{
    const float* x      = (const float*)d_in[0];
    const float* W_in   = (const float*)d_in[1];
    const float* conv_w = (const float*)d_in[2];
    const float* conv_b = (const float*)d_in[3];
    const float* W_xproj= (const float*)d_in[4];
    const float* W_dt   = (const float*)d_in[5];
    const float* b_dt   = (const float*)d_in[6];
    const float* A_log  = (const float*)d_in[7];
    const float* Dv     = (const float*)d_in[8];
    const float* W_out  = (const float*)d_in[9];
    const float* gamma  = (const float*)d_in[10];
    const float* beta   = (const float*)d_in[11];

    char* ws = (char*)d_ws;
    // [0,16.78M): xc (s1-2) -> g3p (s3) / xdh,xdl (s3.5-4) -> hbuf + W_out splits (s5+)
    u16*   xc    = (u16*)(ws);
    float* g3p   = (float*)(ws);                 // 8 x 1.57 MB
    u16*   xdh   = (u16*)(ws + 12582912);
    u16*   xdl   = (u16*)(ws + 14155776);
    float* hbuf  = (float*)(ws);                 // 8.39 MB (s5+)
    u16*   wouth = (u16*)(ws + 8388608);         // 4.19 MB (written in scanA, s5)
    u16*   woutl = (u16*)(ws + 12582912);        // 4.19 MB (xdh/xdl dead by s5)
    // [16.78M,50.33M): z (s1->s5C); then opre partials 0,1 (s6-7)
    float* z     = (float*)(ws + 16777216);
    float* opre  = (float*)(ws + 16777216);      // 2 x 16.78 MB partials (s6-7)
    // [50.33M,67.11M): u (s2->s5C)
    u16*   u     = (u16*)(ws + 50331648);
    // [67.11M,100.66M): x/W_in splits (s0-1) -> delta (s4->s5C)
    u16*   xh    = (u16*)(ws + 67108864);
    u16*   xl    = (u16*)(ws + 75497472);
    u16*   wh    = (u16*)(ws + 83886080);
    u16*   wl    = (u16*)(ws + 92274688);
    float* delta = (float*)(ws + 67108864);
    // [100.66M,104.07M): xdbc + persistent small splits + sdel
    float* xdbc  = (float*)(ws + 100663296);
    u16*   wxh   = (u16*)(ws + 102236160);
    u16*   wxl   = (u16*)(ws + 102629376);
    u16*   wdth  = (u16*)(ws + 103022592);
    u16*   wdtl  = (u16*)(ws + 103284736);
    float* sdel  = (float*)(ws + 103546880);     // 0.52 MB, ends 104.07 MB (< proven 106.4)
    u16*   yb    = (u16*)d_out;

    // 0) pre-splits (x, W_in, W_xproj, W_dt), x4 vectorized, one launch
    megasplit4<<<8512, 256, 0, stream>>>(x, xh, xl, W_in, wh, wl,
                                         W_xproj, wxh, wxl, W_dt, wdth, wdtl);
    // 1) xz = x @ W_in^T -> xc bf16 | z f32   (128^2 tiles, 2 blocks/CU)
    gemm256_xz<<<dim3(32, 32), 256, 0, stream>>>(xh, xl, wh, wl, xc, z);
    // 2) u = silu(conv4(xc)+cb)
    conv_silu<<<4096, 256, 0, stream>>>(xc, conv_w, conv_b, u);
    // 3) gemm3 partials (split-K=8) + combine(-> xdbc, xdh, xdl)
    gemm3_skp<<<dim3(3, 128, 8), 64, 0, stream>>>(
        u, D_INNER, wxh, wxl, D_INNER, g3p, XPROJ_N, 256);
    combine3<<<384, 256, 0, stream>>>(g3p, xdbc, xdh, xdl);
    // 4) delta = softplus(dt @ W_dt^T + b_dt)  (M=4096,N=2048,K=64)
    gemm_dt32<<<dim3(64, 128), 64, 0, stream>>>(
        xdh, xdl, XPROJ_N, wdth, wdtl, DT_RANK, delta, D_INNER, b_dt);
    // 5) chunked parallel scan (partA also splits W_out -> wouth/woutl)
    scan_partA<<<dim3(8, NCHUNK, BSZ), 256, 0, stream>>>(
        delta, u, xdbc, A_log, hbuf, sdel, W_out, wouth, woutl);
    scan_fixup<<<256, 256, 0, stream>>>(hbuf, sdel, A_log);
    scan_partC<<<dim3(8, NCHUNK, BSZ), 256, 0, stream>>>(delta, u, xdbc, z, A_log, Dv, hbuf, yb);
    // 6) opre[kz] = yb @ W_out^T (term-fused, split-K=2, 256 blocks)
    gemm256_out<<<dim3(4, 32, 2), 512, 0, stream>>>(yb, wouth, woutl, opre);
    // 7) layernorm over sum of 2 partials -> d_out f32
    layernorm_kernel<<<4096, 256, 0, stream>>>(opre, gamma, beta, (float*)d_out);
}

// Round 11
// 385.518 us; speedup vs baseline: 1.0439x; 1.0439x over previous
//
#include <hip/hip_runtime.h>
#include <stdint.h>

typedef unsigned short u16;
typedef __bf16 bf16x8 __attribute__((ext_vector_type(8)));
typedef unsigned short u16x8 __attribute__((ext_vector_type(8)));
typedef unsigned short u16x4 __attribute__((ext_vector_type(4)));
typedef float f32x4 __attribute__((ext_vector_type(4)));

#define BSZ 2
#define SEQ 2048
#define DIM 1024
#define D_INNER 2048
#define DT_RANK 64
#define D_STATE 16
#define XPROJ_N 96   // DT_RANK + 2*D_STATE
#define NCHUNK 32
#define CHUNK_T 64   // SEQ / NCHUNK
#define LOG2E 1.44269504f

#define N_X   4194304
#define N_W   4194304
#define N_WX  196608
#define N_WDT 131072
#define N_WO  2097152
#define N_XD  393216

__device__ __forceinline__ float bf2f(u16 h) {
    return __uint_as_float(((unsigned)h) << 16);
}
__device__ __forceinline__ u16 f2bf(float f) {
    unsigned u = __float_as_uint(f);
    unsigned r = (u + 0x7FFFu + ((u >> 16) & 1u)) >> 16;
    return (u16)r;
}

__device__ __forceinline__ f32x4 mfma16(bf16x8 a, bf16x8 b, f32x4 c) {
    return __builtin_amdgcn_mfma_f32_16x16x32_bf16(a, b, c, 0, 0, 0);
}

__device__ __forceinline__ void gload_lds16(const void* g, void* l) {
    __builtin_amdgcn_global_load_lds(
        (const __attribute__((address_space(1))) unsigned int*)(uintptr_t)g,
        (__attribute__((address_space(3))) unsigned int*)(uintptr_t)l,
        16, 0, 0);
}

// vectorized x4 split: f32x4 -> bf16 hi/lo x4
__device__ __forceinline__ void split4(const float* __restrict__ in,
                                       u16* __restrict__ hi, u16* __restrict__ lo,
                                       long i)
{
    f32x4 v = *(const f32x4*)(in + i);
    u16x4 h, l;
    #pragma unroll
    for (int j = 0; j < 4; j++) {
        u16 hh = f2bf(v[j]);
        h[j] = hh;
        l[j] = f2bf(v[j] - bf2f(hh));
    }
    *(u16x4*)(hi + i) = h;
    *(u16x4*)(lo + i) = l;
}

// split x, W_in, W_xproj, W_dt -> bf16 hi/lo, one launch, x4 vectorized
__global__ __launch_bounds__(256)
void megasplit4(const float* __restrict__ x,  u16* __restrict__ xh,  u16* __restrict__ xl,
                const float* __restrict__ w,  u16* __restrict__ wh,  u16* __restrict__ wl,
                const float* __restrict__ wx, u16* __restrict__ wxh, u16* __restrict__ wxl,
                const float* __restrict__ wd, u16* __restrict__ wdh, u16* __restrict__ wdl)
{
    long i = ((long)blockIdx.x * 256 + threadIdx.x) * 4;
    if (i < N_X) { split4(x, xh, xl, i); return; }
    i -= N_X;
    if (i < N_W) { split4(w, wh, wl, i); return; }
    i -= N_W;
    if (i < N_WX) { split4(wx, wxh, wxl, i); return; }
    i -= N_WX;
    if (i < N_WDT) { split4(wd, wdh, wdl, i); }
}

// phase sync brackets (m201 discipline, proven in R2)
#define PH_TOP                                                                \
    __builtin_amdgcn_sched_barrier(0);                                        \
    __builtin_amdgcn_s_barrier();                                             \
    asm volatile("s_waitcnt lgkmcnt(0)" ::: "memory");                        \
    __builtin_amdgcn_sched_barrier(0);                                        \
    __builtin_amdgcn_s_setprio(1);
#define PH_BOT                                                                \
    __builtin_amdgcn_s_setprio(0);                                            \
    __builtin_amdgcn_sched_barrier(0);                                        \
    __builtin_amdgcn_s_barrier();

// ===================== GEMM1: 256x256 tile, TERM-FUSED, 6-phase K-loop ======
// (R9-proven: 89.5us, MfmaUtil 49%, FETCH 73.9MB, 0 conflicts. R10's 128^2
//  2-blocks/CU variant regressed to 96.1 — reverted. Four schedule
//  restructures falsified on this kernel: R3, R6, R10, +R9 traffic-cut
//  showing L2 absorption. This structure is the banked best.)
// xz = x @ W_in^T, 3-term hi/lo emulation (ah*bh + ah*bl + al*bh).
// Stage each physical tile's {AH,AL,BH,BL} ONCE; 6 barrier-bracketed
// 16-MFMA phases; fbh fragments held live across the tile (R8).
__global__ __launch_bounds__(512, 2)
void gemm256_xz(const u16* __restrict__ xh, const u16* __restrict__ xl,
                const u16* __restrict__ wh, const u16* __restrict__ wl,
                u16* __restrict__ xc, float* __restrict__ z)
{
    __shared__ u16 lds[65536];   // 2 slots x 32768 u16 (64KB)

    const int tid  = threadIdx.x;
    const int w    = tid >> 6;
    const int lane = tid & 63;
    const int r16  = lane & 15;
    const int quad = lane >> 4;
    const int wr   = w >> 2;     // 0..1 : rows wr*128..+127
    const int wc   = w & 3;      // 0..3 : cols wc*64..+63
    const long m0  = (long)blockIdx.y * 256;
    const long n0  = (long)blockIdx.x * 256;

    // staging cells: 1024 cells (256 rows x 4 kc) of 16B; thread covers c0,c1
    const int c0 = tid, c1 = tid + 512;
    const int ma0 = c0 >> 2, kc0 = ((c0 & 3) ^ ((ma0 >> 1) & 3)) * 8;
    const int ma1 = c1 >> 2, kc1 = ((c1 & 3) ^ ((ma1 >> 1) & 3)) * 8;
    const int arow0 = ((int)m0 + ma0) * DIM + kc0;
    const int arow1 = ((int)m0 + ma1) * DIM + kc1;
    const int brow0 = ((int)n0 + ma0) * DIM + kc0;
    const int brow1 = ((int)n0 + ma1) * DIM + kc1;

    // fragment read offsets (u16 units)
    int caof[8], cbof[4];
    #pragma unroll
    for (int i = 0; i < 8; i++) {
        int m = wr * 128 + i * 16 + r16;
        caof[i] = (m * 4 + (quad ^ ((m >> 1) & 3))) * 8;
    }
    #pragma unroll
    for (int j = 0; j < 4; j++) {
        int n = wc * 64 + j * 16 + r16;
        cbof[j] = (n * 4 + (quad ^ ((n >> 1) & 3))) * 8;
    }

    f32x4 acc[8][4];
    #pragma unroll
    for (int i = 0; i < 8; i++)
        #pragma unroll
        for (int j = 0; j < 4; j++) acc[i][j] = {0.f, 0.f, 0.f, 0.f};

    // prologue: stage tile 0 fully into slot 0 (AH, AL, BH, BL)
    gload_lds16(xh + arow0, lds + c0 * 8);
    gload_lds16(xh + arow1, lds + c1 * 8);
    gload_lds16(xl + arow0, lds + 8192 + c0 * 8);
    gload_lds16(xl + arow1, lds + 8192 + c1 * 8);
    gload_lds16(wh + brow0, lds + 16384 + c0 * 8);
    gload_lds16(wh + brow1, lds + 16384 + c1 * 8);
    gload_lds16(wl + brow0, lds + 24576 + c0 * 8);
    gload_lds16(wl + brow1, lds + 24576 + c1 * 8);
    asm volatile("s_waitcnt vmcnt(0)" ::: "memory");
    __builtin_amdgcn_s_barrier();

    int kt = 0;
#define XZ_FTILE(CUR, SN)                                                     \
  {                                                                           \
    int st = kt + 1; if (st > 31) st = 31;                                    \
    const int kb = st * 32;                                                   \
    const u16* AHp = lds + (CUR) * 32768;                                     \
    const u16* ALp = AHp + 8192;                                              \
    const u16* BHp = AHp + 16384;                                             \
    const u16* BLp = AHp + 24576;                                             \
    u16* Sb = lds + (SN) * 32768;                                             \
    bf16x8 a0[4], a1[4], fbh[4], fbl[4];                                      \
    /* P1: {bh, ah03 ; stage AH(st)} | MFMA lo x bh */                        \
    _Pragma("unroll") for (int j = 0; j < 4; j++)                             \
        fbh[j] = *(const bf16x8*)(BHp + cbof[j]);                             \
    _Pragma("unroll") for (int i = 0; i < 4; i++)                             \
        a0[i] = *(const bf16x8*)(AHp + caof[i]);                              \
    gload_lds16(xh + arow0 + kb, Sb + c0 * 8);                                \
    gload_lds16(xh + arow1 + kb, Sb + c1 * 8);                                \
    PH_TOP                                                                    \
    _Pragma("unroll") for (int i = 0; i < 4; i++)                             \
      _Pragma("unroll") for (int j = 0; j < 4; j++)                           \
        acc[i][j] = mfma16(a0[i], fbh[j], acc[i][j]);                         \
    PH_BOT                                                                    \
    /* P2: {ah47 ; stage AL(st)} | MFMA hi x bh */                            \
    _Pragma("unroll") for (int i = 0; i < 4; i++)                             \
        a1[i] = *(const bf16x8*)(AHp + caof[4 + i]);                          \
    gload_lds16(xl + arow0 + kb, Sb + 8192 + c0 * 8);                         \
    gload_lds16(xl + arow1 + kb, Sb + 8192 + c1 * 8);                         \
    PH_TOP                                                                    \
    _Pragma("unroll") for (int i = 0; i < 4; i++)                             \
      _Pragma("unroll") for (int j = 0; j < 4; j++)                           \
        acc[4 + i][j] = mfma16(a1[i], fbh[j], acc[4 + i][j]);                 \
    PH_BOT                                                                    \
    /* P3: {bl ; stage BH(st)} | MFMA lo x bl (a0 held) */                    \
    _Pragma("unroll") for (int j = 0; j < 4; j++)                             \
        fbl[j] = *(const bf16x8*)(BLp + cbof[j]);                             \
    gload_lds16(wh + brow0 + kb, Sb + 16384 + c0 * 8);                        \
    gload_lds16(wh + brow1 + kb, Sb + 16384 + c1 * 8);                        \
    PH_TOP                                                                    \
    _Pragma("unroll") for (int i = 0; i < 4; i++)                             \
      _Pragma("unroll") for (int j = 0; j < 4; j++)                           \
        acc[i][j] = mfma16(a0[i], fbl[j], acc[i][j]);                         \
    PH_BOT                                                                    \
    /* P4: {stage BL(st)} | MFMA hi x bl (a1 held) */                         \
    gload_lds16(wl + brow0 + kb, Sb + 24576 + c0 * 8);                        \
    gload_lds16(wl + brow1 + kb, Sb + 24576 + c1 * 8);                        \
    PH_TOP                                                                    \
    _Pragma("unroll") for (int i = 0; i < 4; i++)                             \
      _Pragma("unroll") for (int j = 0; j < 4; j++)                           \
        acc[4 + i][j] = mfma16(a1[i], fbl[j], acc[4 + i][j]);                 \
    PH_BOT                                                                    \
    /* P5: {al03} | MFMA lo x bh (fbh kept live, no re-read) */               \
    _Pragma("unroll") for (int i = 0; i < 4; i++)                             \
        a0[i] = *(const bf16x8*)(ALp + caof[i]);                              \
    PH_TOP                                                                    \
    _Pragma("unroll") for (int i = 0; i < 4; i++)                             \
      _Pragma("unroll") for (int j = 0; j < 4; j++)                           \
        acc[i][j] = mfma16(a0[i], fbh[j], acc[i][j]);                         \
    PH_BOT                                                                    \
    /* P6: {al47} | MFMA hi x bh | vmcnt(0) tile boundary */                  \
    _Pragma("unroll") for (int i = 0; i < 4; i++)                             \
        a1[i] = *(const bf16x8*)(ALp + caof[4 + i]);                          \
    PH_TOP                                                                    \
    _Pragma("unroll") for (int i = 0; i < 4; i++)                             \
      _Pragma("unroll") for (int j = 0; j < 4; j++)                           \
        acc[4 + i][j] = mfma16(a1[i], fbh[j], acc[4 + i][j]);                 \
    __builtin_amdgcn_s_setprio(0);                                            \
    __builtin_amdgcn_sched_barrier(0);                                        \
    asm volatile("s_waitcnt vmcnt(0)" ::: "memory");                          \
    __builtin_amdgcn_s_barrier();                                             \
    kt++;                                                                     \
  }

    #pragma unroll 1
    for (int it = 0; it < 16; it++) {
        XZ_FTILE(0, 1)
        XZ_FTILE(1, 0)
    }
#undef XZ_FTILE

    asm volatile("s_waitcnt vmcnt(0)" ::: "memory");  // drain before endpgm

    // epilogue: cols [0,2048) -> xc bf16, [2048,4096) -> z f32 (block-uniform)
    const bool isz = (n0 >= 2048);
    #pragma unroll
    for (int i = 0; i < 8; i++) {
        #pragma unroll
        for (int j = 0; j < 4; j++) {
            long col = n0 + wc * 64 + j * 16 + r16;
            #pragma unroll
            for (int r = 0; r < 4; r++) {
                long row = m0 + wr * 128 + i * 16 + quad * 4 + r;
                if (!isz) xc[row * (long)D_INNER + col] = f2bf(acc[i][j][r]);
                else      z[row * (long)D_INNER + (col - D_INNER)] = acc[i][j][r];
            }
        }
    }
}

// ===================== GEMM4: term-fused, split-K=2 (R9-proven) =============
// opre[kz] = yb[:,half_kz] @ (Wh + Wl)[:,half_kz]^T — both hi/lo terms per
// block into ONE accumulator, A staged once per K-tile.
// Geometry: BM=128, BN=256, 8 waves (2M x 4N, 64x64/wave, acc[4][4]),
// grid (4,32,2) = 256 blocks. LDS: 2 slots x {A 8KB | Bh 16KB | Bl 16KB}.
__global__ __launch_bounds__(512, 2)
void gemm256_out(const u16* __restrict__ A, const u16* __restrict__ Bh,
                 const u16* __restrict__ Bl, float* __restrict__ OutBase)
{
    __shared__ u16 lds[40960];   // 2 slots x 20480 u16

    const int tid  = threadIdx.x;
    const int w    = tid >> 6;
    const int lane = tid & 63;
    const int r16  = lane & 15;
    const int quad = lane >> 4;
    const int wr   = w >> 2;           // 0..1 : rows wr*64
    const int wc   = w & 3;            // 0..3 : cols wc*64
    const long m0  = (long)blockIdx.y * 128;
    const long n0  = (long)blockIdx.x * 256;
    const int  kz  = blockIdx.z;
    const int  kbase = kz * 1024;
    float* Out = OutBase + (long)kz * 4194304;

    // A staging: 512 cells (128 rows x 4 kc), thread stages 1 cell
    const int maA = tid >> 2, kcA = ((tid & 3) ^ ((maA >> 1) & 3)) * 8;
    const int arow = ((int)m0 + maA) * D_INNER + kbase + kcA;
    // B staging: 1024 cells (256 rows x 4 kc), thread stages c0, c1
    const int c0 = tid, c1 = tid + 512;
    const int mb0 = c0 >> 2, kb0 = ((c0 & 3) ^ ((mb0 >> 1) & 3)) * 8;
    const int mb1 = c1 >> 2, kb1 = ((c1 & 3) ^ ((mb1 >> 1) & 3)) * 8;
    const int brow0 = ((int)n0 + mb0) * D_INNER + kbase + kb0;
    const int brow1 = ((int)n0 + mb1) * D_INNER + kbase + kb1;

    int caof[4], cbof[4];
    #pragma unroll
    for (int i = 0; i < 4; i++) {
        int m = wr * 64 + i * 16 + r16;
        caof[i] = (m * 4 + (quad ^ ((m >> 1) & 3))) * 8;
    }
    #pragma unroll
    for (int j = 0; j < 4; j++) {
        int n = wc * 64 + j * 16 + r16;
        cbof[j] = (n * 4 + (quad ^ ((n >> 1) & 3))) * 8;
    }

    f32x4 acc[4][4];
    #pragma unroll
    for (int i = 0; i < 4; i++)
        #pragma unroll
        for (int j = 0; j < 4; j++) acc[i][j] = {0.f, 0.f, 0.f, 0.f};

    // prologue: stage tile 0 -> slot 0
    gload_lds16(A  + arow,  lds + tid * 8);
    gload_lds16(Bh + brow0, lds + 4096 + c0 * 8);
    gload_lds16(Bh + brow1, lds + 4096 + c1 * 8);
    gload_lds16(Bl + brow0, lds + 12288 + c0 * 8);
    gload_lds16(Bl + brow1, lds + 12288 + c1 * 8);
    asm volatile("s_waitcnt vmcnt(0)" ::: "memory");
    __builtin_amdgcn_s_barrier();

    int kt = 0;
#define O2_TILE(CUR, SN)                                                      \
  {                                                                           \
    int st = kt + 1; if (st > 31) st = 31;                                    \
    const int kb = st * 32;                                                   \
    const u16* Ap  = lds + (CUR) * 20480;                                     \
    const u16* BHp = Ap + 4096;                                               \
    const u16* BLp = Ap + 12288;                                              \
    u16* Sb = lds + (SN) * 20480;                                             \
    bf16x8 fa[4], fb[4];                                                      \
    /* P1: {bh4, a4 ; stage A(st)} | 16 MFMA a x bh */                        \
    _Pragma("unroll") for (int j = 0; j < 4; j++)                             \
        fb[j] = *(const bf16x8*)(BHp + cbof[j]);                              \
    _Pragma("unroll") for (int i = 0; i < 4; i++)                             \
        fa[i] = *(const bf16x8*)(Ap + caof[i]);                               \
    gload_lds16(A + arow + kb, Sb + tid * 8);                                 \
    PH_TOP                                                                    \
    _Pragma("unroll") for (int i = 0; i < 4; i++)                             \
      _Pragma("unroll") for (int j = 0; j < 4; j++)                           \
        acc[i][j] = mfma16(fa[i], fb[j], acc[i][j]);                          \
    PH_BOT                                                                    \
    /* P2: {bl4 ; stage Bh,Bl(st)} | 16 MFMA a x bl | vmcnt(0) */             \
    _Pragma("unroll") for (int j = 0; j < 4; j++)                             \
        fb[j] = *(const bf16x8*)(BLp + cbof[j]);                              \
    gload_lds16(Bh + brow0 + kb, Sb + 4096 + c0 * 8);                         \
    gload_lds16(Bh + brow1 + kb, Sb + 4096 + c1 * 8);                         \
    gload_lds16(Bl + brow0 + kb, Sb + 12288 + c0 * 8);                        \
    gload_lds16(Bl + brow1 + kb, Sb + 12288 + c1 * 8);                        \
    PH_TOP                                                                    \
    _Pragma("unroll") for (int i = 0; i < 4; i++)                             \
      _Pragma("unroll") for (int j = 0; j < 4; j++)                           \
        acc[i][j] = mfma16(fa[i], fb[j], acc[i][j]);                          \
    __builtin_amdgcn_s_setprio(0);                                            \
    __builtin_amdgcn_sched_barrier(0);                                        \
    asm volatile("s_waitcnt vmcnt(0)" ::: "memory");                          \
    __builtin_amdgcn_s_barrier();                                             \
    kt++;                                                                     \
  }

    #pragma unroll 1
    for (int it = 0; it < 16; it++) {
        O2_TILE(0, 1)
        O2_TILE(1, 0)
    }
#undef O2_TILE

    asm volatile("s_waitcnt vmcnt(0)" ::: "memory");

    #pragma unroll
    for (int i = 0; i < 4; i++) {
        #pragma unroll
        for (int j = 0; j < 4; j++) {
            long col = n0 + wc * 64 + j * 16 + r16;
            #pragma unroll
            for (int r = 0; r < 4; r++) {
                long row = m0 + wr * 64 + i * 16 + quad * 4 + r;
                Out[row * (long)DIM + col] = acc[i][j][r];
            }
        }
    }
}

// GEMM2 (K=64): 32x32 per wave, 3-term, softplus epilogue
__global__ __launch_bounds__(64)
void gemm_dt32(const u16* __restrict__ Ah, const u16* __restrict__ Al, int lda,
               const u16* __restrict__ Bh, const u16* __restrict__ Bl, int ldb,
               float* __restrict__ C, int ldc, const float* __restrict__ bias)
{
    const int lane = threadIdx.x;
    const int r16  = lane & 15;
    const int quad = lane >> 4;
    const long m0 = (long)blockIdx.y * 32;
    const long n0 = (long)blockIdx.x * 32;

    const u16* Ah0 = Ah + (m0 + r16) * (long)lda + quad * 8;
    const u16* Ah1 = Ah0 + 16L * lda;
    const u16* Al0 = Al + (m0 + r16) * (long)lda + quad * 8;
    const u16* Al1 = Al0 + 16L * lda;
    const u16* Bh0 = Bh + (n0 + r16) * (long)ldb + quad * 8;
    const u16* Bh1 = Bh0 + 16L * ldb;
    const u16* Bl0 = Bl + (n0 + r16) * (long)ldb + quad * 8;
    const u16* Bl1 = Bl0 + 16L * ldb;

    f32x4 acc00 = {0,0,0,0}, acc01 = {0,0,0,0}, acc10 = {0,0,0,0}, acc11 = {0,0,0,0};

    #pragma unroll
    for (int k = 0; k < DT_RANK; k += 32) {
        bf16x8 a0h = *(const bf16x8*)(Ah0 + k);
        bf16x8 a1h = *(const bf16x8*)(Ah1 + k);
        bf16x8 a0l = *(const bf16x8*)(Al0 + k);
        bf16x8 a1l = *(const bf16x8*)(Al1 + k);
        bf16x8 b0h = *(const bf16x8*)(Bh0 + k);
        bf16x8 b1h = *(const bf16x8*)(Bh1 + k);
        bf16x8 b0l = *(const bf16x8*)(Bl0 + k);
        bf16x8 b1l = *(const bf16x8*)(Bl1 + k);
        acc00 = mfma16(a0h, b0h, acc00); acc00 = mfma16(a0h, b0l, acc00); acc00 = mfma16(a0l, b0h, acc00);
        acc01 = mfma16(a0h, b1h, acc01); acc01 = mfma16(a0h, b1l, acc01); acc01 = mfma16(a0l, b1h, acc01);
        acc10 = mfma16(a1h, b0h, acc10); acc10 = mfma16(a1h, b0l, acc10); acc10 = mfma16(a1l, b0h, acc10);
        acc11 = mfma16(a1h, b1h, acc11); acc11 = mfma16(a1h, b1l, acc11); acc11 = mfma16(a1l, b1h, acc11);
    }

    #pragma unroll
    for (int i = 0; i < 2; i++) {
        #pragma unroll
        for (int j = 0; j < 2; j++) {
            f32x4 v = (i == 0) ? (j == 0 ? acc00 : acc01) : (j == 0 ? acc10 : acc11);
            long col = n0 + j * 16 + r16;
            #pragma unroll
            for (int r = 0; r < 4; r++) {
                long row = m0 + i * 16 + quad * 4 + r;
                float x = v[r] + bias[col];
                x = (x > 15.f) ? x : log1pf(__expf(x));
                C[row * (long)ldc + col] = x;
            }
        }
    }
}

// GEMM3: partial[kz] = u @ W_xproj^T over K-slice kz (no atomics)
__global__ __launch_bounds__(64)
void gemm3_skp(const u16* __restrict__ A, int lda,
               const u16* __restrict__ Bh, const u16* __restrict__ Bl, int ldb,
               float* __restrict__ Cpart, int ldc, int K0)
{
    const int lane = threadIdx.x;
    const int r16  = lane & 15;
    const int quad = lane >> 4;
    const long m0 = (long)blockIdx.y * 32;
    const long n0 = (long)blockIdx.x * 32;
    const int kbase = blockIdx.z * K0;
    float* C = Cpart + (long)blockIdx.z * N_XD;

    const u16* Ap0 = A  + (m0 + r16) * (long)lda + quad * 8 + kbase;
    const u16* Ap1 = Ap0 + 16L * lda;
    const u16* Bh0 = Bh + (n0 + r16) * (long)ldb + quad * 8 + kbase;
    const u16* Bh1 = Bh0 + 16L * ldb;
    const u16* Bl0 = Bl + (n0 + r16) * (long)ldb + quad * 8 + kbase;
    const u16* Bl1 = Bl0 + 16L * ldb;

    f32x4 acc00 = {0,0,0,0}, acc01 = {0,0,0,0}, acc10 = {0,0,0,0}, acc11 = {0,0,0,0};

    for (int k = 0; k < K0; k += 32) {
        bf16x8 a0 = *(const bf16x8*)(Ap0 + k);
        bf16x8 a1 = *(const bf16x8*)(Ap1 + k);
        bf16x8 b0h = *(const bf16x8*)(Bh0 + k);
        bf16x8 b1h = *(const bf16x8*)(Bh1 + k);
        bf16x8 b0l = *(const bf16x8*)(Bl0 + k);
        bf16x8 b1l = *(const bf16x8*)(Bl1 + k);
        acc00 = mfma16(a0, b0h, acc00); acc00 = mfma16(a0, b0l, acc00);
        acc01 = mfma16(a0, b1h, acc01); acc01 = mfma16(a0, b1l, acc01);
        acc10 = mfma16(a1, b0h, acc10); acc10 = mfma16(a1, b0l, acc10);
        acc11 = mfma16(a1, b1h, acc11); acc11 = mfma16(a1, b1l, acc11);
    }

    #pragma unroll
    for (int i = 0; i < 2; i++) {
        #pragma unroll
        for (int j = 0; j < 2; j++) {
            f32x4 v = (i == 0) ? (j == 0 ? acc00 : acc01) : (j == 0 ? acc10 : acc11);
            long col = n0 + j * 16 + r16;
            #pragma unroll
            for (int r = 0; r < 4; r++) {
                long row = m0 + i * 16 + quad * 4 + r;
                C[row * (long)ldc + col] = v[r];
            }
        }
    }
}

// combine 8 gemm3 partials -> xdbc f32 + hi/lo split, x4 vectorized
__global__ __launch_bounds__(256)
void combine3(const float* __restrict__ part, float* __restrict__ xdbc,
              u16* __restrict__ hi, u16* __restrict__ lo)
{
    long i = ((long)blockIdx.x * 256 + threadIdx.x) * 4;
    if (i >= N_XD) return;
    f32x4 s = *(const f32x4*)(part + i);
    #pragma unroll
    for (int j = 1; j < 8; j++) {
        f32x4 p = *(const f32x4*)(part + (long)j * N_XD + i);
        s[0] += p[0]; s[1] += p[1]; s[2] += p[2]; s[3] += p[3];
    }
    *(f32x4*)(xdbc + i) = s;
    u16x4 h, l;
    #pragma unroll
    for (int j = 0; j < 4; j++) {
        u16 hh = f2bf(s[j]);
        h[j] = hh;
        l[j] = f2bf(s[j] - bf2f(hh));
    }
    *(u16x4*)(hi + i) = h;
    *(u16x4*)(lo + i) = l;
}

// depthwise causal conv(4) + bias + silu, 8 channels per thread
__global__ __launch_bounds__(256)
void conv_silu(const u16* __restrict__ xc, const float* __restrict__ cw,
               const float* __restrict__ cb, u16* __restrict__ u)
{
    long idx = ((long)blockIdx.x * 256 + threadIdx.x) * 8;
    int t  = (int)((idx >> 11) & 2047);
    int d0 = (int)(idx & 2047);

    bf16x8 xrow[4];
    #pragma unroll
    for (int j = 0; j < 4; j++) {
        int tt = t - 3 + j;
        if (tt >= 0) xrow[j] = *(const bf16x8*)(xc + idx + (long)(j - 3) * D_INNER);
        else         xrow[j] = bf16x8{0,0,0,0,0,0,0,0};
    }
    u16x8 out;
    #pragma unroll
    for (int e = 0; e < 8; e++) {
        int d = d0 + e;
        float acc = cb[d];
        #pragma unroll
        for (int j = 0; j < 4; j++)
            acc += cw[d * 4 + j] * (float)xrow[j][e];
        out[e] = f2bf(acc / (1.f + __expf(-acc)));
    }
    *(u16x8*)(u + idx) = out;
}

// ---- chunked parallel scan: pass A  (+ fused W_out hi/lo split) ------------
// R7-proven q-power fast path (guarded): Af[s] = (s+1)*Af[0] =>
// exp2(dl*Af[s]) = q^(s+1), ONE exp2 per t.
__global__ __launch_bounds__(256)
void scan_partA(const float* __restrict__ delta, const u16* __restrict__ u,
                const float* __restrict__ xdbc, const float* __restrict__ A_log,
                float* __restrict__ hbuf, float* __restrict__ sdelta,
                const float* __restrict__ wout, u16* __restrict__ wouth,
                u16* __restrict__ woutl)
{
    const int d = blockIdx.x * 256 + threadIdx.x;
    const int c = blockIdx.y;
    const int b = blockIdx.z;
    const int t0 = c * CHUNK_T;

    float Af[16];
    #pragma unroll
    for (int s = 0; s < 16; s++) Af[s] = -__expf(A_log[d * 16 + s]) * LOG2E;
    bool fast = true;
    #pragma unroll
    for (int s = 0; s < 16; s++)
        fast = fast && (fabsf(Af[s] - (float)(s + 1) * Af[0]) < 1e-3f * (float)(s + 1));

    float h[16];
    #pragma unroll
    for (int s = 0; s < 16; s++) h[s] = 0.f;
    float sd = 0.f;

    const float* dptr = delta + ((long)b * SEQ + t0) * D_INNER + d;
    const u16*   uptr = u     + ((long)b * SEQ + t0) * D_INNER + d;
    const float* xp   = xdbc  + ((long)b * SEQ + t0) * XPROJ_N;

    if (fast) {
        const float Af0 = Af[0];
        for (int t = 0; t < CHUNK_T; t++) {
            float dl = dptr[(long)t * D_INNER];
            float uu = bf2f(uptr[(long)t * D_INNER]);
            f32x4 B0 = *(const f32x4*)(xp + t * XPROJ_N + DT_RANK);
            f32x4 B1 = *(const f32x4*)(xp + t * XPROJ_N + DT_RANK + 4);
            f32x4 B2 = *(const f32x4*)(xp + t * XPROJ_N + DT_RANK + 8);
            f32x4 B3 = *(const f32x4*)(xp + t * XPROJ_N + DT_RANK + 12);
            float Bv[16] = {B0[0],B0[1],B0[2],B0[3], B1[0],B1[1],B1[2],B1[3],
                            B2[0],B2[1],B2[2],B2[3], B3[0],B3[1],B3[2],B3[3]};
            sd += dl;
            float dlu = dl * uu;
            float q = exp2f(dl * Af0);
            float dAc = 1.f;
            #pragma unroll
            for (int s = 0; s < 16; s++) {
                dAc *= q;
                h[s] = h[s] * dAc + dlu * Bv[s];
            }
        }
    } else {
        for (int t = 0; t < CHUNK_T; t++) {
            float dl = dptr[(long)t * D_INNER];
            float uu = bf2f(uptr[(long)t * D_INNER]);
            f32x4 B0 = *(const f32x4*)(xp + t * XPROJ_N + DT_RANK);
            f32x4 B1 = *(const f32x4*)(xp + t * XPROJ_N + DT_RANK + 4);
            f32x4 B2 = *(const f32x4*)(xp + t * XPROJ_N + DT_RANK + 8);
            f32x4 B3 = *(const f32x4*)(xp + t * XPROJ_N + DT_RANK + 12);
            float Bv[16] = {B0[0],B0[1],B0[2],B0[3], B1[0],B1[1],B1[2],B1[3],
                            B2[0],B2[1],B2[2],B2[3], B3[0],B3[1],B3[2],B3[3]};
            sd += dl;
            float dlu = dl * uu;
            #pragma unroll
            for (int s = 0; s < 16; s++)
                h[s] = h[s] * exp2f(dl * Af[s]) + dlu * Bv[s];
        }
    }

    float* hout = hbuf + ((long)(b * NCHUNK + c) * D_INNER + d) * 16;
    #pragma unroll
    for (int s = 0; s < 16; s++) hout[s] = h[s];
    sdelta[(long)(b * NCHUNK + c) * D_INNER + d] = sd;

    // fused W_out split: 131072 threads x 16 elems = 2097152 (exact)
    long tidg = (((long)b * NCHUNK + c) * 8 + blockIdx.x) * 256 + threadIdx.x;
    long base = tidg * 16;
    #pragma unroll
    for (int k = 0; k < 4; k++) split4(wout, wouth, woutl, base + 4 * k);
}

// ---- pass B: compose chunk boundaries (in-place: hbuf h_end -> h_in) ----
__global__ __launch_bounds__(256)
void scan_fixup(float* __restrict__ hbuf, const float* __restrict__ sdelta,
                const float* __restrict__ A_log)
{
    const int idx = blockIdx.x * 256 + threadIdx.x;
    const int ds = idx & (D_INNER * 16 - 1);
    const int b  = idx >> 15;
    const float Af = -__expf(A_log[ds]) * LOG2E;
    float hin = 0.f;
    #pragma unroll 4
    for (int c = 0; c < NCHUNK; c++) {
        long gi = (long)(b * NCHUNK + c) * (D_INNER * 16) + ds;
        float e = hbuf[gi];
        hbuf[gi] = hin;
        float sd = sdelta[(long)(b * NCHUNK + c) * D_INNER + (ds >> 4)];
        hin = e + exp2f(Af * sd) * hin;
    }
}

// ---- pass C: full scan from h_in, fused +u*D and *silu(z), write y (bf16) --
// Same q-power fast path as partA (guarded).
__global__ __launch_bounds__(256)
void scan_partC(const float* __restrict__ delta, const u16* __restrict__ u,
                const float* __restrict__ xdbc, const float* __restrict__ z,
                const float* __restrict__ A_log, const float* __restrict__ Dp,
                const float* __restrict__ hbuf, u16* __restrict__ y)
{
    const int d = blockIdx.x * 256 + threadIdx.x;
    const int c = blockIdx.y;
    const int b = blockIdx.z;
    const int t0 = c * CHUNK_T;

    float Af[16];
    #pragma unroll
    for (int s = 0; s < 16; s++) Af[s] = -__expf(A_log[d * 16 + s]) * LOG2E;
    bool fast = true;
    #pragma unroll
    for (int s = 0; s < 16; s++)
        fast = fast && (fabsf(Af[s] - (float)(s + 1) * Af[0]) < 1e-3f * (float)(s + 1));
    const float Dd = Dp[d];

    float h[16];
    const float* hin = hbuf + ((long)(b * NCHUNK + c) * D_INNER + d) * 16;
    #pragma unroll
    for (int s = 0; s < 16; s++) h[s] = hin[s];

    const float* dptr = delta + ((long)b * SEQ + t0) * D_INNER + d;
    const u16*   uptr = u     + ((long)b * SEQ + t0) * D_INNER + d;
    const float* zptr = z     + ((long)b * SEQ + t0) * D_INNER + d;
    const float* xp   = xdbc  + ((long)b * SEQ + t0) * XPROJ_N;
    u16* yptr = y + ((long)b * SEQ + t0) * D_INNER + d;

    if (fast) {
        const float Af0 = Af[0];
        for (int t = 0; t < CHUNK_T; t++) {
            float dl = dptr[(long)t * D_INNER];
            float uu = bf2f(uptr[(long)t * D_INNER]);
            float zl = zptr[(long)t * D_INNER];
            f32x4 B0 = *(const f32x4*)(xp + t * XPROJ_N + DT_RANK);
            f32x4 B1 = *(const f32x4*)(xp + t * XPROJ_N + DT_RANK + 4);
            f32x4 B2 = *(const f32x4*)(xp + t * XPROJ_N + DT_RANK + 8);
            f32x4 B3 = *(const f32x4*)(xp + t * XPROJ_N + DT_RANK + 12);
            f32x4 C0 = *(const f32x4*)(xp + t * XPROJ_N + DT_RANK + 16);
            f32x4 C1 = *(const f32x4*)(xp + t * XPROJ_N + DT_RANK + 20);
            f32x4 C2 = *(const f32x4*)(xp + t * XPROJ_N + DT_RANK + 24);
            f32x4 C3 = *(const f32x4*)(xp + t * XPROJ_N + DT_RANK + 28);
            float Bv[16] = {B0[0],B0[1],B0[2],B0[3], B1[0],B1[1],B1[2],B1[3],
                            B2[0],B2[1],B2[2],B2[3], B3[0],B3[1],B3[2],B3[3]};
            float Cv[16] = {C0[0],C0[1],C0[2],C0[3], C1[0],C1[1],C1[2],C1[3],
                            C2[0],C2[1],C2[2],C2[3], C3[0],C3[1],C3[2],C3[3]};
            float dlu = dl * uu;
            float q = exp2f(dl * Af0);
            float dAc = 1.f;
            float p0 = 0.f, p1 = 0.f, p2 = 0.f, p3 = 0.f;
            #pragma unroll
            for (int s = 0; s < 16; s += 4) {
                float dA0 = dAc * q;
                float dA1 = dA0 * q;
                float dA2 = dA1 * q;
                float dA3 = dA2 * q;
                dAc = dA3;
                h[s]   = h[s]   * dA0 + dlu * Bv[s];
                h[s+1] = h[s+1] * dA1 + dlu * Bv[s+1];
                h[s+2] = h[s+2] * dA2 + dlu * Bv[s+2];
                h[s+3] = h[s+3] * dA3 + dlu * Bv[s+3];
                p0 += h[s]   * Cv[s];
                p1 += h[s+1] * Cv[s+1];
                p2 += h[s+2] * Cv[s+2];
                p3 += h[s+3] * Cv[s+3];
            }
            float acc = (p0 + p1) + (p2 + p3);
            float sz = zl / (1.f + __expf(-zl));
            float yy = (acc + uu * Dd) * sz;
            yptr[(long)t * D_INNER] = f2bf(yy);
        }
    } else {
        for (int t = 0; t < CHUNK_T; t++) {
            float dl = dptr[(long)t * D_INNER];
            float uu = bf2f(uptr[(long)t * D_INNER]);
            float zl = zptr[(long)t * D_INNER];
            f32x4 B0 = *(const f32x4*)(xp + t * XPROJ_N + DT_RANK);
            f32x4 B1 = *(const f32x4*)(xp + t * XPROJ_N + DT_RANK + 4);
            f32x4 B2 = *(const f32x4*)(xp + t * XPROJ_N + DT_RANK + 8);
            f32x4 B3 = *(const f32x4*)(xp + t * XPROJ_N + DT_RANK + 12);
            f32x4 C0 = *(const f32x4*)(xp + t * XPROJ_N + DT_RANK + 16);
            f32x4 C1 = *(const f32x4*)(xp + t * XPROJ_N + DT_RANK + 20);
            f32x4 C2 = *(const f32x4*)(xp + t * XPROJ_N + DT_RANK + 24);
            f32x4 C3 = *(const f32x4*)(xp + t * XPROJ_N + DT_RANK + 28);
            float Bv[16] = {B0[0],B0[1],B0[2],B0[3], B1[0],B1[1],B1[2],B1[3],
                            B2[0],B2[1],B2[2],B2[3], B3[0],B3[1],B3[2],B3[3]};
            float Cv[16] = {C0[0],C0[1],C0[2],C0[3], C1[0],C1[1],C1[2],C1[3],
                            C2[0],C2[1],C2[2],C2[3], C3[0],C3[1],C3[2],C3[3]};
            float dlu = dl * uu;
            float p0 = 0.f, p1 = 0.f, p2 = 0.f, p3 = 0.f;
            #pragma unroll
            for (int s = 0; s < 16; s += 4) {
                h[s]   = h[s]   * exp2f(dl * Af[s])   + dlu * Bv[s];
                h[s+1] = h[s+1] * exp2f(dl * Af[s+1]) + dlu * Bv[s+1];
                h[s+2] = h[s+2] * exp2f(dl * Af[s+2]) + dlu * Bv[s+2];
                h[s+3] = h[s+3] * exp2f(dl * Af[s+3]) + dlu * Bv[s+3];
                p0 += h[s]   * Cv[s];
                p1 += h[s+1] * Cv[s+1];
                p2 += h[s+2] * Cv[s+2];
                p3 += h[s+3] * Cv[s+3];
            }
            float acc = (p0 + p1) + (p2 + p3);
            float sz = zl / (1.f + __expf(-zl));
            float yy = (acc + uu * Dd) * sz;
            yptr[(long)t * D_INNER] = f2bf(yy);
        }
    }
}

// layernorm over sum of 2 split-K partials (stride 4194304 floats apart)
__global__ __launch_bounds__(256)
void layernorm_kernel(const float* __restrict__ p0,
                      const float* __restrict__ gamma, const float* __restrict__ beta,
                      float* __restrict__ out)
{
    const long row = blockIdx.x;
    const long base = row * DIM;
    int tid = threadIdx.x;
    float v[4];
    float sum = 0.f, sq = 0.f;
    #pragma unroll
    for (int i = 0; i < 4; i++) {
        long c = base + tid + i * 256;
        v[i] = p0[c] + p0[c + 4194304];
        sum += v[i];
        sq  += v[i] * v[i];
    }
    #pragma unroll
    for (int off = 1; off < 64; off <<= 1) {
        sum += __shfl_xor(sum, off);
        sq  += __shfl_xor(sq, off);
    }
    __shared__ float ssum[4], ssq[4];
    int w = tid >> 6;
    if ((tid & 63) == 0) { ssum[w] = sum; ssq[w] = sq; }
    __syncthreads();
    float ts = ssum[0] + ssum[1] + ssum[2] + ssum[3];
    float tq = ssq[0] + ssq[1] + ssq[2] + ssq[3];
    float mean = ts * (1.f / DIM);
    float var  = tq * (1.f / DIM) - mean * mean;
    float rstd = rsqrtf(var + 1e-5f);
    float* o = out + base;
    #pragma unroll
    for (int i = 0; i < 4; i++) {
        int c = tid + i * 256;
        o[c] = (v[i] - mean) * rstd * gamma[c] + beta[c];
    }
}

extern "C" void kernel_launch(void* const* d_in, const int* in_sizes, int n_in,
                              void* d_out, int out_size, void* d_ws, size_t ws_size,
                              hipStream_t stream)
{
    const float* x      = (const float*)d_in[0];
    const float* W_in   = (const float*)d_in[1];
    const float* conv_w = (const float*)d_in[2];
    const float* conv_b = (const float*)d_in[3];
    const float* W_xproj= (const float*)d_in[4];
    const float* W_dt   = (const float*)d_in[5];
    const float* b_dt   = (const float*)d_in[6];
    const float* A_log  = (const float*)d_in[7];
    const float* Dv     = (const float*)d_in[8];
    const float* W_out  = (const float*)d_in[9];
    const float* gamma  = (const float*)d_in[10];
    const float* beta   = (const float*)d_in[11];

    char* ws = (char*)d_ws;
    // [0,16.78M): xc (s1-2) -> g3p (s3) / xdh,xdl (s3.5-4) -> hbuf + W_out splits (s5+)
    u16*   xc    = (u16*)(ws);
    float* g3p   = (float*)(ws);                 // 8 x 1.57 MB
    u16*   xdh   = (u16*)(ws + 12582912);
    u16*   xdl   = (u16*)(ws + 14155776);
    float* hbuf  = (float*)(ws);                 // 8.39 MB (s5+)
    u16*   wouth = (u16*)(ws + 8388608);         // 4.19 MB (written in scanA, s5)
    u16*   woutl = (u16*)(ws + 12582912);        // 4.19 MB (xdh/xdl dead by s5)
    // [16.78M,50.33M): z (s1->s5C); then opre partials 0,1 (s6-7)
    float* z     = (float*)(ws + 16777216);
    float* opre  = (float*)(ws + 16777216);      // 2 x 16.78 MB partials (s6-7)
    // [50.33M,67.11M): u (s2->s5C)
    u16*   u     = (u16*)(ws + 50331648);
    // [67.11M,100.66M): x/W_in splits (s0-1) -> delta (s4->s5C)
    u16*   xh    = (u16*)(ws + 67108864);
    u16*   xl    = (u16*)(ws + 75497472);
    u16*   wh    = (u16*)(ws + 83886080);
    u16*   wl    = (u16*)(ws + 92274688);
    float* delta = (float*)(ws + 67108864);
    // [100.66M,104.07M): xdbc + persistent small splits + sdel
    float* xdbc  = (float*)(ws + 100663296);
    u16*   wxh   = (u16*)(ws + 102236160);
    u16*   wxl   = (u16*)(ws + 102629376);
    u16*   wdth  = (u16*)(ws + 103022592);
    u16*   wdtl  = (u16*)(ws + 103284736);
    float* sdel  = (float*)(ws + 103546880);     // 0.52 MB, ends 104.07 MB (< proven 106.4)
    u16*   yb    = (u16*)d_out;

    // 0) pre-splits (x, W_in, W_xproj, W_dt), x4 vectorized, one launch
    megasplit4<<<8512, 256, 0, stream>>>(x, xh, xl, W_in, wh, wl,
                                         W_xproj, wxh, wxl, W_dt, wdth, wdtl);
    // 1) xz = x @ W_in^T -> xc bf16 | z f32   (M=4096,N=4096,K=1024, 3-term fused)
    gemm256_xz<<<dim3(16, 16), 512, 0, stream>>>(xh, xl, wh, wl, xc, z);
    // 2) u = silu(conv4(xc)+cb)
    conv_silu<<<4096, 256, 0, stream>>>(xc, conv_w, conv_b, u);
    // 3) gemm3 partials (split-K=8) + combine(-> xdbc, xdh, xdl)
    gemm3_skp<<<dim3(3, 128, 8), 64, 0, stream>>>(
        u, D_INNER, wxh, wxl, D_INNER, g3p, XPROJ_N, 256);
    combine3<<<384, 256, 0, stream>>>(g3p, xdbc, xdh, xdl);
    // 4) delta = softplus(dt @ W_dt^T + b_dt)  (M=4096,N=2048,K=64)
    gemm_dt32<<<dim3(64, 128), 64, 0, stream>>>(
        xdh, xdl, XPROJ_N, wdth, wdtl, DT_RANK, delta, D_INNER, b_dt);
    // 5) chunked parallel scan (partA also splits W_out -> wouth/woutl)
    scan_partA<<<dim3(8, NCHUNK, BSZ), 256, 0, stream>>>(
        delta, u, xdbc, A_log, hbuf, sdel, W_out, wouth, woutl);
    scan_fixup<<<256, 256, 0, stream>>>(hbuf, sdel, A_log);
    scan_partC<<<dim3(8, NCHUNK, BSZ), 256, 0, stream>>>(delta, u, xdbc, z, A_log, Dv, hbuf, yb);
    // 6) opre[kz] = yb @ W_out^T (term-fused, split-K=2, 256 blocks)
    gemm256_out<<<dim3(4, 32, 2), 512, 0, stream>>>(yb, wouth, woutl, opre);
    // 7) layernorm over sum of 2 partials -> d_out f32
    layernorm_kernel<<<4096, 256, 0, stream>>>(opre, gamma, beta, (float*)d_out);
}